// Round 5
// baseline (1151.263 us; speedup 1.0000x reference)
//
#include <hip/hip_runtime.h>

#define T_TOK 4096
#define DIM   2048
#define IDIM  1408
#define NEXP  16
#define TOPK  2
#define CAP   1024

typedef short  short8  __attribute__((ext_vector_type(8)));
typedef __bf16 bf16x8  __attribute__((ext_vector_type(8)));
typedef float  f32x4   __attribute__((ext_vector_type(4)));

__device__ inline float bf2f(unsigned short h) {
    union { unsigned u; float f; } v; v.u = ((unsigned)h) << 16; return v.f;
}
__device__ inline unsigned short f2bf_bits(float f) {
    __bf16 h = (__bf16)f;
    return __builtin_bit_cast(unsigned short, h);
}
__device__ inline f32x4 mfma16(short8 a, short8 b, f32x4 c) {
    return __builtin_amdgcn_mfma_f32_16x16x32_bf16(a, b, c, 0, 0, 0);
}

// ---------------- Gate: fp32 logits -> sqrt(softplus) -> top2 ----------------
__global__ __launch_bounds__(256) void gate_kernel(
    const float* __restrict__ X, const float* __restrict__ GW,
    const float* __restrict__ GB, int* __restrict__ outIdx, float* __restrict__ outW)
{
    const int wid  = threadIdx.x >> 6;
    const int lane = threadIdx.x & 63;
    const int t    = blockIdx.x * 4 + wid;
    const float* xr = X + (size_t)t * DIM;
    float xv[32];
#pragma unroll
    for (int i = 0; i < 32; ++i) xv[i] = xr[lane + i * 64];
    float s[16];
    for (int e = 0; e < 16; ++e) {
        const float* gr = GW + e * DIM;
        float p = 0.f;
#pragma unroll
        for (int i = 0; i < 32; ++i) p += xv[i] * gr[lane + i * 64];
#pragma unroll
        for (int off = 32; off >= 1; off >>= 1) p += __shfl_xor(p, off);
        s[e] = p;
    }
    if (lane == 0) {
        float sc[16], sel[16];
#pragma unroll
        for (int e = 0; e < 16; ++e) {
            float lg = s[e];
            float sp = fmaxf(lg, 0.f) + log1pf(expf(-fabsf(lg)));  // stable softplus
            sc[e]  = sqrtf(sp);
            sel[e] = sc[e] + GB[e];
        }
        int b0 = 0; float v0 = sel[0];
#pragma unroll
        for (int e = 1; e < 16; ++e) if (sel[e] > v0) { v0 = sel[e]; b0 = e; }
        int b1 = -1; float v1 = -1e30f;
#pragma unroll
        for (int e = 0; e < 16; ++e) if (e != b0 && sel[e] > v1) { v1 = sel[e]; b1 = e; }
        float a = sc[b0], b = sc[b1];
        float inv = 1.f / (a + b);
        outIdx[t * 2]     = b0;
        outIdx[t * 2 + 1] = b1;
        outW[t * 2]       = a * inv;
        outW[t * 2 + 1]   = b * inv;
    }
}

// ---------------- Route: atomic slot assignment per expert ----------------
__global__ void route_kernel(const int* __restrict__ idx, int* __restrict__ cnt,
                             int* __restrict__ lists, int* __restrict__ slotOf)
{
    int p = blockIdx.x * 256 + threadIdx.x;
    if (p >= T_TOK * TOPK) return;
    int e = idx[p];
    int s = atomicAdd(&cnt[e], 1);
    if (s < CAP) { lists[e * CAP + s] = p; slotOf[p] = s; }
    else slotOf[p] = -1;
}

// ---------------- Grouped GEMM (128x128x64 tiles, bf16 MFMA) ----------------
// DUAL=true : FFN1  H = silu(A@W1^T) * (A@W3^T), A = gathered fp32 x rows
// DUAL=false: FFN2  out = A@W2^T,               A = bf16 H rows
template<bool DUAL, bool ABF>
__global__ __launch_bounds__(256, 2) void ffn_gemm(
    const float* __restrict__ X, const unsigned short* __restrict__ Hin,
    const float* __restrict__ We1, const float* __restrict__ We3,
    const float* __restrict__ Wsh1, const float* __restrict__ Wsh3,
    const int* __restrict__ lists, const int* __restrict__ counts,
    unsigned short* __restrict__ Hout, unsigned short* __restrict__ OutB,
    float* __restrict__ Yout, int KD, int ND)
{
    const int g = blockIdx.z;
    int cnt = (g < NEXP) ? counts[g] : T_TOK;
    if (cnt > CAP && g < NEXP) cnt = CAP;
    const int m0 = blockIdx.y * 128;
    if (m0 >= cnt) return;
    const int n0 = blockIdx.x * 128;
    const int t  = threadIdx.x;

    __shared__ __align__(16) unsigned short As[8192];
    __shared__ __align__(16) unsigned short Bs[8192];
    __shared__ __align__(16) unsigned short B3s[DUAL ? 8192 : 16];

    const int rl = t >> 3;   // 0..31 local row of this thread's staging chunk
    const int c8 = t & 7;    // which 8-element chunk in the 64-wide K slab

    const float* w1base = (g < NEXP) ? We1 + (size_t)g * ND * KD : Wsh1;
    const float* w3base = nullptr;
    if constexpr (DUAL) w3base = (g < NEXP) ? We3 + (size_t)g * ND * KD : Wsh3;
    const int hbase = (g < NEXP) ? g * CAP : NEXP * CAP;

    const float* aF[4];
    const unsigned short* aH[4];
    const float* bP[4];
    const float* b3P[4];
#pragma unroll
    for (int it = 0; it < 4; ++it) {
        int r = rl + it * 32;
        if constexpr (ABF) {
            aH[it] = Hin + (size_t)(hbase + m0 + r) * KD;
        } else {
            int tok;
            if (g < NEXP) {
                int mm = m0 + r; if (mm > cnt - 1) mm = cnt - 1;
                tok = lists[g * CAP + mm] >> 1;
            } else tok = m0 + r;
            aF[it] = X + (size_t)tok * KD;
        }
        int br = n0 + r;
        bP[it] = w1base + (size_t)br * KD;
        if constexpr (DUAL) b3P[it] = w3base + (size_t)br * KD;
    }

    const int wid = t >> 6, lane = t & 63;
    const int wm = (wid >> 1) * 64, wn = (wid & 1) * 64;
    const int lr = lane & 15, lg = lane >> 4;

    f32x4 accG[4][4] = {};
    f32x4 accU[4][4] = {};

    const int ksteps = KD >> 6;
    for (int kt = 0; kt < ksteps; ++kt) {
        const int kb = kt << 6;
        // ---- stage (fp32 -> bf16 conversion, XOR-swizzled LDS) ----
#pragma unroll
        for (int it = 0; it < 4; ++it) {
            const int r  = rl + it * 32;
            const int sw = r * 128 + ((c8 * 16) ^ ((r & 7) << 4));
            if constexpr (ABF) {
                short8 sv = *(const short8*)(aH[it] + kb + c8 * 8);
                *(short8*)((char*)As + sw) = sv;
            } else {
                const float* p = aF[it] + kb + c8 * 8;
                float4 v0 = *(const float4*)p, v1 = *(const float4*)(p + 4);
                bf16x8 bv;
                bv[0] = (__bf16)v0.x; bv[1] = (__bf16)v0.y; bv[2] = (__bf16)v0.z; bv[3] = (__bf16)v0.w;
                bv[4] = (__bf16)v1.x; bv[5] = (__bf16)v1.y; bv[6] = (__bf16)v1.z; bv[7] = (__bf16)v1.w;
                *(short8*)((char*)As + sw) = __builtin_bit_cast(short8, bv);
            }
            {
                const float* p = bP[it] + kb + c8 * 8;
                float4 v0 = *(const float4*)p, v1 = *(const float4*)(p + 4);
                bf16x8 bv;
                bv[0] = (__bf16)v0.x; bv[1] = (__bf16)v0.y; bv[2] = (__bf16)v0.z; bv[3] = (__bf16)v0.w;
                bv[4] = (__bf16)v1.x; bv[5] = (__bf16)v1.y; bv[6] = (__bf16)v1.z; bv[7] = (__bf16)v1.w;
                *(short8*)((char*)Bs + sw) = __builtin_bit_cast(short8, bv);
            }
            if constexpr (DUAL) {
                const float* p = b3P[it] + kb + c8 * 8;
                float4 v0 = *(const float4*)p, v1 = *(const float4*)(p + 4);
                bf16x8 bv;
                bv[0] = (__bf16)v0.x; bv[1] = (__bf16)v0.y; bv[2] = (__bf16)v0.z; bv[3] = (__bf16)v0.w;
                bv[4] = (__bf16)v1.x; bv[5] = (__bf16)v1.y; bv[6] = (__bf16)v1.z; bv[7] = (__bf16)v1.w;
                *(short8*)((char*)B3s + sw) = __builtin_bit_cast(short8, bv);
            }
        }
        __syncthreads();
        // ---- compute: 16x16x32 bf16 MFMA, 64x64 per wave ----
#pragma unroll
        for (int s = 0; s < 2; ++s) {
            short8 av[4];
#pragma unroll
            for (int i = 0; i < 4; ++i) {
                int row = wm + i * 16 + lr;
                int ad  = row * 128 + ((s * 64 + lg * 16) ^ ((row & 7) << 4));
                av[i] = *(const short8*)((const char*)As + ad);
            }
#pragma unroll
            for (int j = 0; j < 4; ++j) {
                int brow = wn + j * 16 + lr;
                int bd   = brow * 128 + ((s * 64 + lg * 16) ^ ((brow & 7) << 4));
                short8 bv = *(const short8*)((const char*)Bs + bd);
                if constexpr (DUAL) {
                    short8 b3 = *(const short8*)((const char*)B3s + bd);
#pragma unroll
                    for (int i = 0; i < 4; ++i) {
                        accG[i][j] = mfma16(av[i], bv, accG[i][j]);
                        accU[i][j] = mfma16(av[i], b3, accU[i][j]);
                    }
                } else {
#pragma unroll
                    for (int i = 0; i < 4; ++i)
                        accG[i][j] = mfma16(av[i], bv, accG[i][j]);
                }
            }
        }
        __syncthreads();
    }

    // ---- epilogue (C/D layout: col=lane&15, row=(lane>>4)*4+reg) ----
    if constexpr (DUAL) {
#pragma unroll
        for (int i = 0; i < 4; ++i)
#pragma unroll
        for (int j = 0; j < 4; ++j) {
            f32x4 gv = accG[i][j], uv = accU[i][j];
            int col = n0 + wn + j * 16 + lr;
#pragma unroll
            for (int r = 0; r < 4; ++r) {
                int row = m0 + wm + i * 16 + lg * 4 + r;
                float gg = gv[r];
                float hv = (gg / (1.f + expf(-gg))) * uv[r];   // silu(g)*u
                Hout[(size_t)(hbase + row) * ND + col] = f2bf_bits(hv);
            }
        }
    } else {
#pragma unroll
        for (int i = 0; i < 4; ++i)
#pragma unroll
        for (int j = 0; j < 4; ++j) {
            f32x4 v = accG[i][j];
            int col = n0 + wn + j * 16 + lr;
#pragma unroll
            for (int r = 0; r < 4; ++r) {
                int row = m0 + wm + i * 16 + lg * 4 + r;
                if (g < NEXP)
                    OutB[(size_t)(g * CAP + row) * DIM + col] = f2bf_bits(v[r]);
                else
                    Yout[(size_t)row * DIM + col] = v[r];      // shared -> d_out
            }
        }
    }
}

// ---------------- Combine: y[t] = shared[t] + sum_k w * OutB[e_k, slot_k] ----
__global__ __launch_bounds__(256) void combine_kernel(
    const unsigned short* __restrict__ OutB, const int* __restrict__ idx,
    const float* __restrict__ w, const int* __restrict__ slotOf, float* __restrict__ Y)
{
    int gid = blockIdx.x * 256 + threadIdx.x;      // 4096*512 threads, 4 floats each
    int t = gid >> 9;
    int d = (gid & 511) << 2;
    float4 acc = *(float4*)(Y + (size_t)t * DIM + d);
#pragma unroll
    for (int k = 0; k < 2; ++k) {
        int s = slotOf[t * 2 + k];
        if (s >= 0) {
            int e = idx[t * 2 + k];
            float wk = w[t * 2 + k];
            const unsigned short* rp = OutB + (size_t)(e * CAP + s) * DIM + d;
            acc.x += wk * bf2f(rp[0]);
            acc.y += wk * bf2f(rp[1]);
            acc.z += wk * bf2f(rp[2]);
            acc.w += wk * bf2f(rp[3]);
        }
    }
    *(float4*)(Y + (size_t)t * DIM + d) = acc;
}

extern "C" void kernel_launch(void* const* d_in, const int* in_sizes, int n_in,
                              void* d_out, int out_size, void* d_ws, size_t ws_size,
                              hipStream_t stream) {
    const float* x   = (const float*)d_in[0];
    // d_in[1] = input_ids (int64) — unused by the reference computation
    const float* gw  = (const float*)d_in[2];
    const float* gb  = (const float*)d_in[3];
    const float* W1  = (const float*)d_in[4];
    const float* W3  = (const float*)d_in[5];
    const float* W2  = (const float*)d_in[6];
    const float* Ws1 = (const float*)d_in[7];
    const float* Ws3 = (const float*)d_in[8];
    const float* Ws2 = (const float*)d_in[9];
    float* y = (float*)d_out;

    char* ws = (char*)d_ws;
    int*   d_idx  = (int*)(ws);                         // 8192 ints
    float* d_w    = (float*)(ws + 32768);               // 8192 floats
    int*   d_cnt  = (int*)(ws + 65536);                 // 16 ints (+pad)
    int*   d_list = (int*)(ws + 65792);                 // 16*1024 ints
    int*   d_slot = (int*)(ws + 131328);                // 8192 ints
    unsigned short* d_H    = (unsigned short*)(ws + 164096);     // 20480 x 1408 bf16
    unsigned short* d_OutB = (unsigned short*)(ws + 57835776);   // 16384 x 2048 bf16

    hipMemsetAsync(d_cnt, 0, 64, stream);
    gate_kernel<<<1024, 256, 0, stream>>>(x, gw, gb, d_idx, d_w);
    route_kernel<<<32, 256, 0, stream>>>(d_idx, d_cnt, d_list, d_slot);
    // FFN1: A = gathered x rows (fp32), K=2048, N=1408, dual W1/W3 + SwiGLU
    ffn_gemm<true, false><<<dim3(11, 32, 17), 256, 0, stream>>>(
        x, nullptr, W1, W3, Ws1, Ws3, d_list, d_cnt, d_H, nullptr, nullptr, DIM, IDIM);
    // FFN2: A = H rows (bf16), K=1408, N=2048; shared group writes d_out directly
    ffn_gemm<false, true><<<dim3(16, 32, 17), 256, 0, stream>>>(
        nullptr, d_H, W2, nullptr, Ws2, nullptr, d_list, d_cnt, nullptr, d_OutB, y, IDIM, DIM);
    combine_kernel<<<8192, 256, 0, stream>>>(d_OutB, d_idx, d_w, d_slot, y);
}